// Round 3
// baseline (380.367 us; speedup 1.0000x reference)
//
#include <hip/hip_runtime.h>
#include <stdint.h>

// Problem constants (fixed by the reference)
#define BATCH   4096
#define IN_DIM  1024
#define OUT_DIM 1024

typedef __bf16 bf16x8 __attribute__((ext_vector_type(8)));
typedef float  f32x4  __attribute__((ext_vector_type(4)));

// fp32 -> bf16 bits, round-to-nearest-even
__device__ __forceinline__ uint16_t f2bf(float f) {
    union { float f; uint32_t u; } v; v.f = f;
    uint32_t u = v.u;
    uint32_t r = (u + 0x7FFFu + ((u >> 16) & 1u)) >> 16;
    return (uint16_t)r;
}

__device__ __forceinline__ float bf2f(uint16_t h) {
    union { uint32_t u; float f; } v; v.u = ((uint32_t)h) << 16;
    return v.f;
}

// ---------------------------------------------------------------------------
// prep: blocks 0..4095   -> convert x row b to bf16, compute alpha[b][0..3]
//       blocks 4096..8191 -> convert W (flat 4M floats) to bf16
//       block 4096 additionally zeroes the 256 per-tile counters.
// ---------------------------------------------------------------------------
__global__ __launch_bounds__(256) void prep(
    const float* __restrict__ x, const float* __restrict__ phase,
    const float* __restrict__ basis, const float* __restrict__ W,
    uint16_t* __restrict__ xb, uint16_t* __restrict__ Wb,
    float* __restrict__ alphaWS, int* __restrict__ tileCnt)
{
    const int bid = blockIdx.x;
    const int tid = threadIdx.x;

    if (bid < BATCH) {
        const int b = bid;
        const float HALF_PI = 1.5707963267948966f;
        float s  = phase[b] / HALF_PI;
        int   q  = (int)floorf(s);
        q = q < 0 ? 0 : (q > 3 ? 3 : q);
        float t  = s - (float)q;
        float t2 = t * t, t3 = t2 * t;

        float coef[4];
#pragma unroll
        for (int j = 0; j < 4; ++j)
            coef[j] = t3 * basis[j] + t2 * basis[4 + j] + t * basis[8 + j] + basis[12 + j];

        // CPI[q][k] = (q+k+3)%4  =>  alpha[c] = coef[(c - q + 1) & 3]
        if (tid < 4) alphaWS[b * 4 + tid] = coef[(tid - q + 1) & 3];

        float4 xv = ((const float4*)(x + (size_t)b * IN_DIM))[tid];
        ushort4 o;
        o.x = f2bf(xv.x); o.y = f2bf(xv.y); o.z = f2bf(xv.z); o.w = f2bf(xv.w);
        ((ushort4*)(xb + (size_t)b * IN_DIM))[tid] = o;
    } else {
        const int j = bid - BATCH;                 // 0..4095, W has 1M float4s
        if (j == 0) tileCnt[tid] = 0;              // zero 256 tile counters
        float4 wv = ((const float4*)W)[j * 256 + tid];
        ushort4 o;
        o.x = f2bf(wv.x); o.y = f2bf(wv.y); o.z = f2bf(wv.z); o.w = f2bf(wv.w);
        ((ushort4*)Wb)[j * 256 + tid] = o;
    }
}

// ---------------------------------------------------------------------------
// gemm_split: P_c[m,n] = bf16( sum_k x[m,k] * W[c,n,k] )   (K = 1024 per c)
// Round-0 proven main loop: 128x128 tile, BK=64, 256 threads (2x2 waves,
// each 64x64 via 4x4 MFMA). grid = (32 M, 8 N, 4 c) = 1024 blocks -> 4/CU.
// LDS XOR swizzle applied on the global source address.
//
// Epilogue: tile-serial split-K reduction (replaces the reduce kernel).
// The 4 c-blocks of tile (bx,by) have linear ids bx+32*by+256*c, congruent
// mod 8 -> same XCD -> partials are L2-local. Each block stores its bf16
// partial, release-fences, increments the tile counter (agent scope); the
// LAST block re-reads all 4 partials (agent-scope 8B atomic loads, bypassing
// potentially-stale L1) and writes out[m,n] = sum_c alpha[m,c]*(P_c+bias[c,n])
// in fp32 — numerically identical to the round-0 reduce kernel.
// ---------------------------------------------------------------------------
__global__ __launch_bounds__(256, 4) void gemm_split(
    const uint16_t* __restrict__ xb, const uint16_t* __restrict__ Wb,
    const float* __restrict__ alphaWS, const float* __restrict__ biases,
    uint16_t* __restrict__ P, int* __restrict__ tileCnt,
    float* __restrict__ out)
{
    __shared__ uint16_t As[128 * 64];
    __shared__ uint16_t Bs[128 * 64];
    __shared__ int sLast;

    const int tid  = threadIdx.x;
    const int lane = tid & 63;
    const int wid  = tid >> 6;
    const int wm   = wid >> 1;
    const int wn   = wid & 1;
    const int tileM = blockIdx.x * 128;
    const int tileN = blockIdx.y * 128;
    const int c     = blockIdx.z;

    f32x4 acc[4][4];
#pragma unroll
    for (int mi = 0; mi < 4; ++mi)
#pragma unroll
        for (int ni = 0; ni < 4; ++ni)
            acc[mi][ni] = (f32x4){0.f, 0.f, 0.f, 0.f};

    // staging: slice s (=wid*4+j) covers rows 8s..8s+7; lane l -> row l>>3,
    // physical chunk l&7; source global chunk = (l&7) ^ (l>>3)  (XOR swizzle)
    const int srow = lane >> 3;
    const int gchunk = ((lane & 7) ^ srow) * 8;   // element offset of 8-elem chunk

    const uint16_t* Ag = xb + (size_t)tileM * 1024;
    const uint16_t* Bg = Wb + ((size_t)c << 20) + (size_t)tileN * 1024;

    const int quad = lane >> 4;
    const int l7   = lane & 7;

    for (int kt = 0; kt < 16; ++kt) {
        const int k0 = kt * 64;
#pragma unroll
        for (int j = 0; j < 4; ++j) {
            const int s = wid * 4 + j;
            const uint16_t* ga = Ag + (size_t)(s * 8 + srow) * 1024 + k0 + gchunk;
            __builtin_amdgcn_global_load_lds(
                (const __attribute__((address_space(1))) void*)ga,
                (__attribute__((address_space(3))) void*)(As + s * 512), 16, 0, 0);
            const uint16_t* gb = Bg + (size_t)(s * 8 + srow) * 1024 + k0 + gchunk;
            __builtin_amdgcn_global_load_lds(
                (const __attribute__((address_space(1))) void*)gb,
                (__attribute__((address_space(3))) void*)(Bs + s * 512), 16, 0, 0);
        }
        __syncthreads();

#pragma unroll
        for (int ks = 0; ks < 2; ++ks) {
            bf16x8 af[4], bfr[4];
#pragma unroll
            for (int mi = 0; mi < 4; ++mi) {
                const int row = wm * 64 + mi * 16 + (lane & 15);
                const int ch  = (ks * 4 + quad) ^ l7;     // physical chunk
                af[mi] = *(const bf16x8*)(As + row * 64 + ch * 8);
            }
#pragma unroll
            for (int ni = 0; ni < 4; ++ni) {
                const int row = wn * 64 + ni * 16 + (lane & 15);
                const int ch  = (ks * 4 + quad) ^ l7;
                bfr[ni] = *(const bf16x8*)(Bs + row * 64 + ch * 8);
            }
#pragma unroll
            for (int mi = 0; mi < 4; ++mi)
#pragma unroll
                for (int ni = 0; ni < 4; ++ni)
                    acc[mi][ni] = __builtin_amdgcn_mfma_f32_16x16x32_bf16(
                        af[mi], bfr[ni], acc[mi][ni], 0, 0, 0);
        }
        __syncthreads();
    }

    // partial store, bf16 (alpha/bias applied in the tile-serial reduction)
    // C/D layout: col = lane&15, row = quad*4 + reg  [m89/m91 verified]
    const size_t stride = (size_t)BATCH * OUT_DIM;
    uint16_t* Pc = P + (size_t)c * stride;
    const int col0 = tileN + wn * 64 + (lane & 15);
#pragma unroll
    for (int mi = 0; mi < 4; ++mi) {
#pragma unroll
        for (int r = 0; r < 4; ++r) {
            const int m = tileM + wm * 64 + mi * 16 + quad * 4 + r;
#pragma unroll
            for (int ni = 0; ni < 4; ++ni)
                Pc[(size_t)m * OUT_DIM + col0 + ni * 16] = f2bf(acc[mi][ni][r]);
        }
    }

    // ---- tile-serial reduction: last of the 4 c-blocks combines ----
    __threadfence();                    // release our partial (device scope)
    __syncthreads();                    // all threads' stores+fences done
    if (tid == 0) {
        int old = __hip_atomic_fetch_add(&tileCnt[blockIdx.y * 32 + blockIdx.x], 1,
                                         __ATOMIC_ACQ_REL, __HIP_MEMORY_SCOPE_AGENT);
        sLast = (old == 3);
    }
    __syncthreads();
    if (!sLast) return;
    __threadfence();                    // acquire side for all threads

    // This tile's 4 partials are L2-hot (same XCD). Thread t: row tid>>1,
    // 64-col half (tid&1). Agent-scope 8B atomic loads bypass stale L1.
    const int row = tid >> 1;
    const int m   = tileM + row;
    const int ch0 = (tid & 1) * 64;
    const float4 al = *(const float4*)(alphaWS + 4 * m);
    const float a[4] = {al.x, al.y, al.z, al.w};
#pragma unroll
    for (int g = 0; g < 16; ++g) {
        const int col = tileN + ch0 + g * 4;
        float4 r = {0.f, 0.f, 0.f, 0.f};
#pragma unroll
        for (int cc = 0; cc < 4; ++cc) {
            unsigned long long pv = __hip_atomic_load(
                (const unsigned long long*)(P + cc * stride + (size_t)m * OUT_DIM + col),
                __ATOMIC_RELAXED, __HIP_MEMORY_SCOPE_AGENT);
            ushort4 p = *(ushort4*)&pv;
            float4 b = *(const float4*)(biases + (size_t)cc * OUT_DIM + col);
            r.x += a[cc] * (bf2f(p.x) + b.x);
            r.y += a[cc] * (bf2f(p.y) + b.y);
            r.z += a[cc] * (bf2f(p.z) + b.z);
            r.w += a[cc] * (bf2f(p.w) + b.w);
        }
        *(float4*)(out + (size_t)m * OUT_DIM + col) = r;
    }
}

extern "C" void kernel_launch(void* const* d_in, const int* in_sizes, int n_in,
                              void* d_out, int out_size, void* d_ws, size_t ws_size,
                              hipStream_t stream)
{
    const float* x       = (const float*)d_in[0];  // (B, IN)
    const float* phase   = (const float*)d_in[1];  // (B,)
    const float* weights = (const float*)d_in[2];  // (4, OUT, IN)
    const float* biases  = (const float*)d_in[3];  // (4, OUT)
    const float* basis   = (const float*)d_in[4];  // (4, 4)
    float* out = (float*)d_out;                    // (B, OUT)

    // Workspace: xb bf16 8 MB | Wb bf16 8 MB | alpha 64 KB | cnt 1 KB | P bf16 32 MB
    uint16_t* xb = (uint16_t*)d_ws;
    uint16_t* Wb = xb + (size_t)BATCH * IN_DIM;
    float* alphaWS = (float*)(Wb + (size_t)4 * OUT_DIM * IN_DIM);
    int* tileCnt = (int*)(alphaWS + (size_t)BATCH * 4);
    uint16_t* P = (uint16_t*)(tileCnt + 256);

    prep<<<2 * BATCH, 256, 0, stream>>>(x, phase, basis, weights, xb, Wb,
                                        alphaWS, tileCnt);

    dim3 grid(BATCH / 128, OUT_DIM / 128, 4);  // M fastest for XCD L2 locality
    gemm_split<<<grid, 256, 0, stream>>>(xb, Wb, alphaWS, biases, P, tileCnt, out);
}

// Round 4
// 331.145 us; speedup vs baseline: 1.1486x; 1.1486x over previous
//
#include <hip/hip_runtime.h>
#include <stdint.h>

// Problem constants (fixed by the reference)
#define BATCH   4096
#define IN_DIM  1024
#define OUT_DIM 1024

typedef __bf16 bf16x8 __attribute__((ext_vector_type(8)));
typedef float  f32x4  __attribute__((ext_vector_type(4)));
typedef unsigned short ushort8v __attribute__((ext_vector_type(8)));

// fp32 -> bf16 bits, round-to-nearest-even
__device__ __forceinline__ uint16_t f2bf(float f) {
    union { float f; uint32_t u; } v; v.f = f;
    uint32_t u = v.u;
    uint32_t r = (u + 0x7FFFu + ((u >> 16) & 1u)) >> 16;
    return (uint16_t)r;
}

__device__ __forceinline__ float bf2f(uint16_t h) {
    union { uint32_t u; float f; } v; v.u = ((uint32_t)h) << 16;
    return v.f;
}

// ---------------------------------------------------------------------------
// prep: blocks 0..4095   -> convert x row b to bf16, compute alpha[b][0..3]
//       blocks 4096..8191 -> convert W (flat 4M floats) to bf16
//       block 4096 additionally zeroes the 256 per-tile counters.
// ---------------------------------------------------------------------------
__global__ __launch_bounds__(256) void prep(
    const float* __restrict__ x, const float* __restrict__ phase,
    const float* __restrict__ basis, const float* __restrict__ W,
    uint16_t* __restrict__ xb, uint16_t* __restrict__ Wb,
    float* __restrict__ alphaWS, int* __restrict__ tileCnt)
{
    const int bid = blockIdx.x;
    const int tid = threadIdx.x;

    if (bid < BATCH) {
        const int b = bid;
        const float HALF_PI = 1.5707963267948966f;
        float s  = phase[b] / HALF_PI;
        int   q  = (int)floorf(s);
        q = q < 0 ? 0 : (q > 3 ? 3 : q);
        float t  = s - (float)q;
        float t2 = t * t, t3 = t2 * t;

        float coef[4];
#pragma unroll
        for (int j = 0; j < 4; ++j)
            coef[j] = t3 * basis[j] + t2 * basis[4 + j] + t * basis[8 + j] + basis[12 + j];

        // CPI[q][k] = (q+k+3)%4  =>  alpha[c] = coef[(c - q + 1) & 3]
        if (tid < 4) alphaWS[b * 4 + tid] = coef[(tid - q + 1) & 3];

        float4 xv = ((const float4*)(x + (size_t)b * IN_DIM))[tid];
        ushort4 o;
        o.x = f2bf(xv.x); o.y = f2bf(xv.y); o.z = f2bf(xv.z); o.w = f2bf(xv.w);
        ((ushort4*)(xb + (size_t)b * IN_DIM))[tid] = o;
    } else {
        const int j = bid - BATCH;                 // 0..4095, W has 1M float4s
        if (j == 0) tileCnt[tid] = 0;              // zero 256 tile counters
        float4 wv = ((const float4*)W)[j * 256 + tid];
        ushort4 o;
        o.x = f2bf(wv.x); o.y = f2bf(wv.y); o.z = f2bf(wv.z); o.w = f2bf(wv.w);
        ((ushort4*)Wb)[j * 256 + tid] = o;
    }
}

// ---------------------------------------------------------------------------
// gemm_split: P_c[m,n] = bf16( sum_k x[m,k] * W[c,n,k] )   (K = 1024 per c)
// Round-0 proven main loop: 128x128 tile, BK=64, 256 threads (2x2 waves,
// each 64x64 via 4x4 MFMA). grid = (32 M, 8 N, 4 c) = 1024 blocks -> 4/CU.
// LDS XOR swizzle applied on the global source address.
//
// Epilogue: tile-serial split-c reduction (replaces the reduce kernel).
// Protocol (XCD-safe, does NOT rely on block->XCD mapping):
//   writer: stores partial -> __threadfence (agent release: L2 writeback)
//           -> syncthreads -> counter atomicAdd ACQ_REL agent scope
//   last:   sees old==3 -> syncthreads -> __threadfence (agent acquire:
//           L1/L2 invalidate) -> PLAIN coalesced loads of the 4 partials.
// Round 3 used 8B agent-scope ATOMIC loads here: UC path, 224 MB HBM fetch,
// +250 us. Plain loads after the acquire fence are equally correct and read
// full 128B lines. Reduction lanes: 16 lanes x 16B chunks = 256B/row segment.
// ---------------------------------------------------------------------------
__global__ __launch_bounds__(256, 4) void gemm_split(
    const uint16_t* __restrict__ xb, const uint16_t* __restrict__ Wb,
    const float* __restrict__ alphaWS, const float* __restrict__ biases,
    uint16_t* __restrict__ P, int* __restrict__ tileCnt,
    float* __restrict__ out)
{
    __shared__ uint16_t As[128 * 64];
    __shared__ uint16_t Bs[128 * 64];
    __shared__ int sLast;

    const int tid  = threadIdx.x;
    const int lane = tid & 63;
    const int wid  = tid >> 6;
    const int wm   = wid >> 1;
    const int wn   = wid & 1;
    const int tileM = blockIdx.x * 128;
    const int tileN = blockIdx.y * 128;
    const int c     = blockIdx.z;

    f32x4 acc[4][4];
#pragma unroll
    for (int mi = 0; mi < 4; ++mi)
#pragma unroll
        for (int ni = 0; ni < 4; ++ni)
            acc[mi][ni] = (f32x4){0.f, 0.f, 0.f, 0.f};

    // staging: slice s (=wid*4+j) covers rows 8s..8s+7; lane l -> row l>>3,
    // physical chunk l&7; source global chunk = (l&7) ^ (l>>3)  (XOR swizzle)
    const int srow = lane >> 3;
    const int gchunk = ((lane & 7) ^ srow) * 8;   // element offset of 8-elem chunk

    const uint16_t* Ag = xb + (size_t)tileM * 1024;
    const uint16_t* Bg = Wb + ((size_t)c << 20) + (size_t)tileN * 1024;

    const int quad = lane >> 4;
    const int l7   = lane & 7;

    for (int kt = 0; kt < 16; ++kt) {
        const int k0 = kt * 64;
#pragma unroll
        for (int j = 0; j < 4; ++j) {
            const int s = wid * 4 + j;
            const uint16_t* ga = Ag + (size_t)(s * 8 + srow) * 1024 + k0 + gchunk;
            __builtin_amdgcn_global_load_lds(
                (const __attribute__((address_space(1))) void*)ga,
                (__attribute__((address_space(3))) void*)(As + s * 512), 16, 0, 0);
            const uint16_t* gb = Bg + (size_t)(s * 8 + srow) * 1024 + k0 + gchunk;
            __builtin_amdgcn_global_load_lds(
                (const __attribute__((address_space(1))) void*)gb,
                (__attribute__((address_space(3))) void*)(Bs + s * 512), 16, 0, 0);
        }
        __syncthreads();

#pragma unroll
        for (int ks = 0; ks < 2; ++ks) {
            bf16x8 af[4], bfr[4];
#pragma unroll
            for (int mi = 0; mi < 4; ++mi) {
                const int row = wm * 64 + mi * 16 + (lane & 15);
                const int ch  = (ks * 4 + quad) ^ l7;     // physical chunk
                af[mi] = *(const bf16x8*)(As + row * 64 + ch * 8);
            }
#pragma unroll
            for (int ni = 0; ni < 4; ++ni) {
                const int row = wn * 64 + ni * 16 + (lane & 15);
                const int ch  = (ks * 4 + quad) ^ l7;
                bfr[ni] = *(const bf16x8*)(Bs + row * 64 + ch * 8);
            }
#pragma unroll
            for (int mi = 0; mi < 4; ++mi)
#pragma unroll
                for (int ni = 0; ni < 4; ++ni)
                    acc[mi][ni] = __builtin_amdgcn_mfma_f32_16x16x32_bf16(
                        af[mi], bfr[ni], acc[mi][ni], 0, 0, 0);
        }
        __syncthreads();
    }

    // partial store, bf16 (alpha/bias applied in the tile-serial reduction)
    // C/D layout: col = lane&15, row = quad*4 + reg  [m89/m91 verified]
    const size_t stride = (size_t)BATCH * OUT_DIM;
    uint16_t* Pc = P + (size_t)c * stride;
    const int col0 = tileN + wn * 64 + (lane & 15);
#pragma unroll
    for (int mi = 0; mi < 4; ++mi) {
#pragma unroll
        for (int r = 0; r < 4; ++r) {
            const int m = tileM + wm * 64 + mi * 16 + quad * 4 + r;
#pragma unroll
            for (int ni = 0; ni < 4; ++ni)
                Pc[(size_t)m * OUT_DIM + col0 + ni * 16] = f2bf(acc[mi][ni][r]);
        }
    }

    // ---- tile-serial reduction: last of the 4 c-blocks combines ----
    __threadfence();                    // agent release: publish our partial
    __syncthreads();                    // all threads' stores+fences done
    if (tid == 0) {
        int old = __hip_atomic_fetch_add(&tileCnt[blockIdx.y * 32 + blockIdx.x], 1,
                                         __ATOMIC_ACQ_REL, __HIP_MEMORY_SCOPE_AGENT);
        sLast = (old == 3);
    }
    __syncthreads();
    if (!sLast) return;
    __threadfence();                    // agent acquire: invalidate L1/L2

    // lanes 0-15 read 16 consecutive 16B chunks of one row (256B segments).
    // rsub walks 16 rows per pass, 8 passes cover the 128-row tile.
    const int rsub = tid >> 4;          // 0..15
    const int chk  = tid & 15;          // 0..15 -> 8-col chunk
    const int colb = tileN + chk * 8;

    // hoist bias tile (independent of row): 4c x 8 cols
    float bias_r[4][8];
#pragma unroll
    for (int cc = 0; cc < 4; ++cc) {
        float4 b0 = *(const float4*)(biases + (size_t)cc * OUT_DIM + colb);
        float4 b1 = *(const float4*)(biases + (size_t)cc * OUT_DIM + colb + 4);
        bias_r[cc][0] = b0.x; bias_r[cc][1] = b0.y; bias_r[cc][2] = b0.z; bias_r[cc][3] = b0.w;
        bias_r[cc][4] = b1.x; bias_r[cc][5] = b1.y; bias_r[cc][6] = b1.z; bias_r[cc][7] = b1.w;
    }

#pragma unroll
    for (int rr = 0; rr < 8; ++rr) {
        const int m = tileM + rr * 16 + rsub;
        const float4 al = *(const float4*)(alphaWS + 4 * m);
        const float a[4] = {al.x, al.y, al.z, al.w};
        float r[8] = {0.f, 0.f, 0.f, 0.f, 0.f, 0.f, 0.f, 0.f};
#pragma unroll
        for (int cc = 0; cc < 4; ++cc) {
            ushort8v p = *(const ushort8v*)(P + cc * stride + (size_t)m * OUT_DIM + colb);
#pragma unroll
            for (int e = 0; e < 8; ++e)
                r[e] += a[cc] * (bf2f(p[e]) + bias_r[cc][e]);
        }
        float4 o0 = {r[0], r[1], r[2], r[3]};
        float4 o1 = {r[4], r[5], r[6], r[7]};
        *(float4*)(out + (size_t)m * OUT_DIM + colb)     = o0;
        *(float4*)(out + (size_t)m * OUT_DIM + colb + 4) = o1;
    }
}

extern "C" void kernel_launch(void* const* d_in, const int* in_sizes, int n_in,
                              void* d_out, int out_size, void* d_ws, size_t ws_size,
                              hipStream_t stream)
{
    const float* x       = (const float*)d_in[0];  // (B, IN)
    const float* phase   = (const float*)d_in[1];  // (B,)
    const float* weights = (const float*)d_in[2];  // (4, OUT, IN)
    const float* biases  = (const float*)d_in[3];  // (4, OUT)
    const float* basis   = (const float*)d_in[4];  // (4, 4)
    float* out = (float*)d_out;                    // (B, OUT)

    // Workspace: xb bf16 8 MB | Wb bf16 8 MB | alpha 64 KB | cnt 1 KB | P bf16 32 MB
    uint16_t* xb = (uint16_t*)d_ws;
    uint16_t* Wb = xb + (size_t)BATCH * IN_DIM;
    float* alphaWS = (float*)(Wb + (size_t)4 * OUT_DIM * IN_DIM);
    int* tileCnt = (int*)(alphaWS + (size_t)BATCH * 4);
    uint16_t* P = (uint16_t*)(tileCnt + 256);

    prep<<<2 * BATCH, 256, 0, stream>>>(x, phase, basis, weights, xb, Wb,
                                        alphaWS, tileCnt);

    dim3 grid(BATCH / 128, OUT_DIM / 128, 4);  // M fastest for XCD L2 locality
    gemm_split<<<grid, 256, 0, stream>>>(xb, Wb, alphaWS, biases, P, tileCnt, out);
}

// Round 6
// 129.995 us; speedup vs baseline: 2.9260x; 2.5474x over previous
//
#include <hip/hip_runtime.h>
#include <stdint.h>

// Problem constants (fixed by the reference)
#define BATCH   4096
#define IN_DIM  1024
#define OUT_DIM 1024

typedef __bf16 bf16x8 __attribute__((ext_vector_type(8)));
typedef float  f32x4  __attribute__((ext_vector_type(4)));

// fp32 -> bf16 bits, round-to-nearest-even
__device__ __forceinline__ uint16_t f2bf(float f) {
    union { float f; uint32_t u; } v; v.f = f;
    uint32_t u = v.u;
    uint32_t r = (u + 0x7FFFu + ((u >> 16) & 1u)) >> 16;
    return (uint16_t)r;
}

__device__ __forceinline__ float bf2f(uint16_t h) {
    union { uint32_t u; float f; } v; v.u = ((uint32_t)h) << 16;
    return v.f;
}

// ---------------------------------------------------------------------------
// prep: blocks 0..4095   -> convert x row b to bf16, compute alpha[b][0..3]
//       blocks 4096..8191 -> convert W (flat 4M floats) to bf16
// (round-0 verified version, tileCnt removed)
// ---------------------------------------------------------------------------
__global__ __launch_bounds__(256) void prep(
    const float* __restrict__ x, const float* __restrict__ phase,
    const float* __restrict__ basis, const float* __restrict__ W,
    uint16_t* __restrict__ xb, uint16_t* __restrict__ Wb,
    float* __restrict__ alphaWS)
{
    const int bid = blockIdx.x;
    const int tid = threadIdx.x;

    if (bid < BATCH) {
        const int b = bid;
        const float HALF_PI = 1.5707963267948966f;
        float s  = phase[b] / HALF_PI;
        int   q  = (int)floorf(s);
        q = q < 0 ? 0 : (q > 3 ? 3 : q);
        float t  = s - (float)q;
        float t2 = t * t, t3 = t2 * t;

        float coef[4];
#pragma unroll
        for (int j = 0; j < 4; ++j)
            coef[j] = t3 * basis[j] + t2 * basis[4 + j] + t * basis[8 + j] + basis[12 + j];

        // CPI[q][k] = (q+k+3)%4  =>  alpha[c] = coef[(c - q + 1) & 3]
        if (tid < 4) alphaWS[b * 4 + tid] = coef[(tid - q + 1) & 3];

        float4 xv = ((const float4*)(x + (size_t)b * IN_DIM))[tid];
        ushort4 o;
        o.x = f2bf(xv.x); o.y = f2bf(xv.y); o.z = f2bf(xv.z); o.w = f2bf(xv.w);
        ((ushort4*)(xb + (size_t)b * IN_DIM))[tid] = o;
    } else {
        const int j = bid - BATCH;                 // 0..4095, W has 1M float4s
        float4 wv = ((const float4*)W)[j * 256 + tid];
        ushort4 o;
        o.x = f2bf(wv.x); o.y = f2bf(wv.y); o.z = f2bf(wv.z); o.w = f2bf(wv.w);
        ((ushort4*)Wb)[j * 256 + tid] = o;
    }
}

// ---------------------------------------------------------------------------
// gemm_fused: one block = one 64x64 out-tile; wave wid computes control
// point c = wid over the SAME tile (A shared, B_c private). After the
// K-loop the 4 c-partials live in the 4 waves of this block -> scale by
// alpha[m,c] in-register, exchange via LDS (bf16, stride-66 pad), add
// alpha-weighted bias, write fp32 out. NO cross-block sync (rounds 2-5:
// atomics / UC loads / fences / cooperative launch all refuted).
//
// Main loop per wave = round-0 verified fragment math (wm=0, 64-row tile):
// 4x4 MFMA 16x16x32 x 2 ks per BK=64 step; XOR swizzle on global source;
// read chunk = (ks*4+quad)^(lane&7). Staging per wave: 2 A-slices + 8
// B-slices (its own c). grid (64,16) = 1024 blocks, LDS 40KB -> 3/CU.
// ---------------------------------------------------------------------------
#define PS 66   // padded row stride (elems) for epilogue exchange

__global__ __launch_bounds__(256, 3) void gemm_fused(
    const uint16_t* __restrict__ xb, const uint16_t* __restrict__ Wb,
    const float* __restrict__ alphaWS, const float* __restrict__ biases,
    float* __restrict__ out)
{
    __shared__ uint16_t lds[64 * 64 + 4 * 64 * 64];   // As 8KB | Bs 32KB (40KB)
    uint16_t* As = lds;                                // [64][64]
    uint16_t* Bs = lds + 4096;                         // [4][64][64]
    uint16_t* Ps = lds;                                // epilogue alias [4][64][PS]

    const int tid  = threadIdx.x;
    const int lane = tid & 63;
    const int wid  = tid >> 6;        // = c for this wave
    const int tileM = blockIdx.x * 64;
    const int tileN = blockIdx.y * 64;

    f32x4 acc[4][4];
#pragma unroll
    for (int mi = 0; mi < 4; ++mi)
#pragma unroll
        for (int ni = 0; ni < 4; ++ni)
            acc[mi][ni] = (f32x4){0.f, 0.f, 0.f, 0.f};

    // staging: slice = 8 rows x 64 cols; lane l -> row l>>3, phys chunk l&7,
    // source global chunk = (l&7) ^ (l>>3)   (XOR swizzle, round-0 verified)
    const int srow = lane >> 3;
    const int gchunk = ((lane & 7) ^ srow) * 8;

    const uint16_t* Ag = xb + (size_t)tileM * 1024;
    const uint16_t* Bg = Wb + ((size_t)wid << 20) + (size_t)tileN * 1024;

    const int quad = lane >> 4;
    const int l7   = lane & 7;

    for (int kt = 0; kt < 16; ++kt) {
        const int k0 = kt * 64;
        // A: 8 slices total, wave stages 2 (shared by all 4 waves)
#pragma unroll
        for (int j = 0; j < 2; ++j) {
            const int s = wid * 2 + j;
            const uint16_t* ga = Ag + (size_t)(s * 8 + srow) * 1024 + k0 + gchunk;
            __builtin_amdgcn_global_load_lds(
                (const __attribute__((address_space(1))) void*)ga,
                (__attribute__((address_space(3))) void*)(As + s * 512), 16, 0, 0);
        }
        // B_c: 8 slices, this wave's own control point
#pragma unroll
        for (int j = 0; j < 8; ++j) {
            const uint16_t* gb = Bg + (size_t)(j * 8 + srow) * 1024 + k0 + gchunk;
            __builtin_amdgcn_global_load_lds(
                (const __attribute__((address_space(1))) void*)gb,
                (__attribute__((address_space(3))) void*)(Bs + wid * 4096 + j * 512), 16, 0, 0);
        }
        __syncthreads();

#pragma unroll
        for (int ks = 0; ks < 2; ++ks) {
            const int ch = (ks * 4 + quad) ^ l7;       // physical chunk
            bf16x8 af[4], bfr[4];
#pragma unroll
            for (int mi = 0; mi < 4; ++mi) {
                const int row = mi * 16 + (lane & 15);
                af[mi] = *(const bf16x8*)(As + row * 64 + ch * 8);
            }
#pragma unroll
            for (int ni = 0; ni < 4; ++ni) {
                const int row = ni * 16 + (lane & 15);
                bfr[ni] = *(const bf16x8*)(Bs + wid * 4096 + row * 64 + ch * 8);
            }
#pragma unroll
            for (int mi = 0; mi < 4; ++mi)
#pragma unroll
                for (int ni = 0; ni < 4; ++ni)
                    acc[mi][ni] = __builtin_amdgcn_mfma_f32_16x16x32_bf16(
                        af[mi], bfr[ni], acc[mi][ni], 0, 0, 0);
        }
        __syncthreads();
    }

    // ---- epilogue: in-block c-reduction ----
    // 1) scale by alpha[m, c=wid] and publish bf16 partials to Ps.
    //    C/D layout: col = lane&15, row(64-tile) = mi*16 + quad*4 + r.
    float av[4][4];
#pragma unroll
    for (int mi = 0; mi < 4; ++mi)
#pragma unroll
        for (int r = 0; r < 4; ++r)
            av[mi][r] = alphaWS[(size_t)(tileM + mi * 16 + quad * 4 + r) * 4 + wid];

#pragma unroll
    for (int mi = 0; mi < 4; ++mi) {
#pragma unroll
        for (int r = 0; r < 4; ++r) {
            const int row = mi * 16 + quad * 4 + r;
#pragma unroll
            for (int ni = 0; ni < 4; ++ni)
                Ps[wid * (64 * PS) + row * PS + ni * 16 + (lane & 15)] =
                    f2bf(av[mi][r] * acc[mi][ni][r]);
        }
    }
    __syncthreads();

    // 2) combine: thread t -> row rr = t>>2, 16-col group cg = t&3.
    //    out[m,n] = sum_c Ps_c[m,n] + sum_c alpha[m,c]*bias[c,n]
    {
        const int rr = tid >> 2;
        const int cg = tid & 3;
        const int colb = cg * 16;
        const float4 al = *(const float4*)(alphaWS + (size_t)(tileM + rr) * 4);
        const float a[4] = {al.x, al.y, al.z, al.w};

        float res[16];
#pragma unroll
        for (int j = 0; j < 16; ++j) res[j] = 0.f;

#pragma unroll
        for (int cc = 0; cc < 4; ++cc) {
            // alpha-weighted bias (bias is L2-hot, 16KB total)
#pragma unroll
            for (int jj = 0; jj < 4; ++jj) {
                float4 bv = *(const float4*)(biases + (size_t)cc * OUT_DIM + tileN + colb + jj * 4);
                res[jj * 4 + 0] += a[cc] * bv.x;
                res[jj * 4 + 1] += a[cc] * bv.y;
                res[jj * 4 + 2] += a[cc] * bv.z;
                res[jj * 4 + 3] += a[cc] * bv.w;
            }
            // partial (ushort2 = 4B aligned: offsets all even)
            const uint16_t* p = Ps + cc * (64 * PS) + rr * PS + colb;
#pragma unroll
            for (int jj = 0; jj < 8; ++jj) {
                uint32_t pv = *(const uint32_t*)(p + jj * 2);
                res[jj * 2 + 0] += bf2f((uint16_t)(pv & 0xFFFFu));
                res[jj * 2 + 1] += bf2f((uint16_t)(pv >> 16));
            }
        }

        float* orow = out + (size_t)(tileM + rr) * OUT_DIM + tileN + colb;
#pragma unroll
        for (int jj = 0; jj < 4; ++jj) {
            float4 o = {res[jj * 4 + 0], res[jj * 4 + 1], res[jj * 4 + 2], res[jj * 4 + 3]};
            *(float4*)(orow + jj * 4) = o;
        }
    }
}

extern "C" void kernel_launch(void* const* d_in, const int* in_sizes, int n_in,
                              void* d_out, int out_size, void* d_ws, size_t ws_size,
                              hipStream_t stream)
{
    const float* x       = (const float*)d_in[0];  // (B, IN)
    const float* phase   = (const float*)d_in[1];  // (B,)
    const float* weights = (const float*)d_in[2];  // (4, OUT, IN)
    const float* biases  = (const float*)d_in[3];  // (4, OUT)
    const float* basis   = (const float*)d_in[4];  // (4, 4)
    float* out = (float*)d_out;                    // (B, OUT)

    // Workspace: xb bf16 8 MB | Wb bf16 8 MB | alpha 64 KB
    uint16_t* xb = (uint16_t*)d_ws;
    uint16_t* Wb = xb + (size_t)BATCH * IN_DIM;
    float* alphaWS = (float*)(Wb + (size_t)4 * OUT_DIM * IN_DIM);

    prep<<<2 * BATCH, 256, 0, stream>>>(x, phase, basis, weights, xb, Wb, alphaWS);

    dim3 grid(BATCH / 64, OUT_DIM / 64);   // 1024 blocks, M-fastest for L2
    gemm_fused<<<grid, 256, 0, stream>>>(xb, Wb, alphaWS, biases, out);
}